// Round 1
// baseline (1728.771 us; speedup 1.0000x reference)
//
#include <hip/hip_runtime.h>

#define ND 128   // node feature dim D
#define ED 32    // edge radial basis dim
#define LN_EPS 1e-5f

// ---------------------------------------------------------------------------
// Detect int64-vs-int32 edge_index layout and convert to packed int32 arrays.
// int64 little-endian: words [lo, hi] with hi==0 (values in [0, 50000)).
// If the first 256 odd words are all zero -> int64 layout. For int32 layout the
// odd words are random node ids; P(all 256 == 0) ~ 0.
// ---------------------------------------------------------------------------
__global__ void conv_idx_kernel(const unsigned* __restrict__ raw,
                                int* __restrict__ ctr, int* __restrict__ ngh,
                                int E) {
    __shared__ int s_is64;
    if (threadIdx.x == 0) {
        unsigned acc = 0;
        for (int i = 1; i < 512; i += 2) acc |= raw[i];
        s_is64 = (acc == 0) ? 1 : 0;
    }
    __syncthreads();
    const int is64 = s_is64;
    const int tid = blockIdx.x * blockDim.x + threadIdx.x;
    const int stride = gridDim.x * blockDim.x;
    if (is64) {
        for (int e = tid; e < E; e += stride) {
            ctr[e] = (int)raw[(size_t)2 * e];
            ngh[e] = (int)raw[(size_t)2 * E + (size_t)2 * e];
        }
    } else {
        for (int e = tid; e < E; e += stride) {
            ctr[e] = (int)raw[e];
            ngh[e] = (int)raw[(size_t)E + e];
        }
    }
}

// ---------------------------------------------------------------------------
// wcc = W_center_node @ W_concat[0:128, :]   (128x128, tiny)
// ---------------------------------------------------------------------------
__global__ void wcc_kernel(const float* __restrict__ Wc,
                           const float* __restrict__ Wcat,
                           float* __restrict__ wcc) {
    const int i = blockIdx.x;    // 128 blocks
    const int j = threadIdx.x;   // 128 threads
    float acc = 0.f;
    for (int k = 0; k < ND; ++k)
        acc += Wc[i * ND + k] * Wcat[k * ND + j];
    wcc[i * ND + j] = acc;
}

// ---------------------------------------------------------------------------
// out[M,128] = A[M,128] @ W[128,128], fp32.
// W staged in LDS (64 KB). 256 threads = 8 groups of 32; each group owns one
// row per iteration; each thread computes 4 consecutive output cols.
// Row values are distributed across the 32 lanes (float4 each) and broadcast
// via __shfl (static lane/index under full unroll -> no scratch).
// ---------------------------------------------------------------------------
__global__ __launch_bounds__(256) void gemm128_kernel(
    const float* __restrict__ A, const float* __restrict__ W,
    float* __restrict__ out, int M) {
    __shared__ float Ws[ND * ND];
    for (int i = threadIdx.x; i < ND * ND; i += 256) Ws[i] = W[i];
    __syncthreads();
    const int slot = threadIdx.x >> 5;        // 0..7 (row within 8-row group)
    const int j0 = (threadIdx.x & 31) * 4;    // 4 consecutive cols
    for (int r0 = blockIdx.x * 8; r0 < M; r0 += gridDim.x * 8) {
        const int r = r0 + slot;
        float rv[4] = {0.f, 0.f, 0.f, 0.f};
        if (r < M) {
            const float4 t = *(const float4*)&A[(size_t)r * ND + j0];
            rv[0] = t.x; rv[1] = t.y; rv[2] = t.z; rv[3] = t.w;
        }
        float4 acc = {0.f, 0.f, 0.f, 0.f};
#pragma unroll
        for (int k = 0; k < ND; ++k) {
            const float a = __shfl(rv[k & 3], k >> 2, 32);
            const float4 w = *(const float4*)&Ws[k * ND + j0];
            acc.x += a * w.x; acc.y += a * w.y;
            acc.z += a * w.z; acc.w += a * w.w;
        }
        if (r < M) *(float4*)&out[(size_t)r * ND + j0] = acc;
    }
}

// ---------------------------------------------------------------------------
// Per edge e: R = edge_attr[e] @ W_edge  (1x32 @ 32x128)
//             m[center[e]] += P[neigh[e]] * R   (elementwise, atomic)
// 64-edge batches staged in LDS. 8 edges in flight (one per 32-lane group).
// Assumes E % 64 == 0 (E = 800000).
// ---------------------------------------------------------------------------
__global__ __launch_bounds__(256) void edge_kernel(
    const float* __restrict__ edge_attr, const int* __restrict__ ctr,
    const int* __restrict__ ngh, const float* __restrict__ W_edge,
    const float* __restrict__ P, float* __restrict__ m, int E) {
    __shared__ float We[ED * ND];      // 16 KB
    __shared__ float ea_s[64][ED];     // 8 KB
    __shared__ int ctr_s[64], ngh_s[64];
    for (int i = threadIdx.x; i < ED * ND; i += 256) We[i] = W_edge[i];
    const int g = threadIdx.x >> 5;        // 0..7
    const int j0 = (threadIdx.x & 31) * 4; // 4 consecutive cols
    for (int e0 = blockIdx.x * 64; e0 < E; e0 += gridDim.x * 64) {
        __syncthreads();
        for (int i = threadIdx.x; i < 64 * ED; i += 256)
            ea_s[i >> 5][i & 31] = edge_attr[(size_t)e0 * ED + i];
        if (threadIdx.x < 64)
            ctr_s[threadIdx.x] = ctr[e0 + threadIdx.x];
        else if (threadIdx.x < 128)
            ngh_s[threadIdx.x - 64] = ngh[e0 + threadIdx.x - 64];
        __syncthreads();
        for (int s = 0; s < 8; ++s) {
            const int slot = s * 8 + g;
            const int nc = ctr_s[slot];
            const int nn = ngh_s[slot];
            float4 r = {0.f, 0.f, 0.f, 0.f};
#pragma unroll
            for (int k = 0; k < ED; ++k) {
                const float a = ea_s[slot][k];            // LDS broadcast
                const float4 w = *(const float4*)&We[k * ND + j0];
                r.x += a * w.x; r.y += a * w.y;
                r.z += a * w.z; r.w += a * w.w;
            }
            const float4 p = *(const float4*)&P[(size_t)nn * ND + j0];
            float* mb = &m[(size_t)nc * ND + j0];
            atomicAdd(mb + 0, r.x * p.x);
            atomicAdd(mb + 1, r.y * p.y);
            atomicAdd(mb + 2, r.z * p.z);
            atomicAdd(mb + 3, r.w * p.w);
        }
    }
}

// ---------------------------------------------------------------------------
// out[r] = LayerNorm(C2[r] + m[r] @ W_bot) * lnw + lnb  (in-place on d_out OK:
// each thread only reads its own C2 elements before writing them).
// ---------------------------------------------------------------------------
__global__ __launch_bounds__(256) void final_kernel(
    const float* __restrict__ C2, const float* __restrict__ m,
    const float* __restrict__ Wb, const float* __restrict__ lnw,
    const float* __restrict__ lnb, float* __restrict__ out, int N) {
    __shared__ float Ws[ND * ND];
    for (int i = threadIdx.x; i < ND * ND; i += 256) Ws[i] = Wb[i];
    __syncthreads();
    const int slot = threadIdx.x >> 5;
    const int j0 = (threadIdx.x & 31) * 4;
    for (int r0 = blockIdx.x * 8; r0 < N; r0 += gridDim.x * 8) {
        const int r = r0 + slot;
        float mv[4] = {0.f, 0.f, 0.f, 0.f};
        float4 acc = {0.f, 0.f, 0.f, 0.f};
        if (r < N) {
            const float4 t = *(const float4*)&m[(size_t)r * ND + j0];
            mv[0] = t.x; mv[1] = t.y; mv[2] = t.z; mv[3] = t.w;
            acc = *(const float4*)&C2[(size_t)r * ND + j0];
        }
#pragma unroll
        for (int k = 0; k < ND; ++k) {
            const float a = __shfl(mv[k & 3], k >> 2, 32);
            const float4 w = *(const float4*)&Ws[k * ND + j0];
            acc.x += a * w.x; acc.y += a * w.y;
            acc.z += a * w.z; acc.w += a * w.w;
        }
        // LayerNorm across the 32 lanes owning this row (4 values each).
        float s = acc.x + acc.y + acc.z + acc.w;
        s += __shfl_xor(s, 16); s += __shfl_xor(s, 8);
        s += __shfl_xor(s, 4);  s += __shfl_xor(s, 2); s += __shfl_xor(s, 1);
        const float mean = s * (1.f / ND);
        const float4 d = {acc.x - mean, acc.y - mean, acc.z - mean, acc.w - mean};
        float q = d.x * d.x + d.y * d.y + d.z * d.z + d.w * d.w;
        q += __shfl_xor(q, 16); q += __shfl_xor(q, 8);
        q += __shfl_xor(q, 4);  q += __shfl_xor(q, 2); q += __shfl_xor(q, 1);
        const float rstd = rsqrtf(q * (1.f / ND) + LN_EPS);
        const float4 w4 = *(const float4*)&lnw[j0];
        const float4 b4 = *(const float4*)&lnb[j0];
        if (r < N) {
            float4 o;
            o.x = d.x * rstd * w4.x + b4.x;
            o.y = d.y * rstd * w4.y + b4.y;
            o.z = d.z * rstd * w4.z + b4.z;
            o.w = d.w * rstd * w4.w + b4.w;
            *(float4*)&out[(size_t)r * ND + j0] = o;
        }
    }
}

// ---------------------------------------------------------------------------
extern "C" void kernel_launch(void* const* d_in, const int* in_sizes, int n_in,
                              void* d_out, int out_size, void* d_ws, size_t ws_size,
                              hipStream_t stream) {
    const float*    node_attr = (const float*)d_in[0];
    const float*    edge_attr = (const float*)d_in[1];
    const unsigned* edge_idx  = (const unsigned*)d_in[2];
    const float*    W_node    = (const float*)d_in[3];
    const float*    W_center  = (const float*)d_in[4];
    const float*    W_concat  = (const float*)d_in[5];
    const float*    W_edge    = (const float*)d_in[6];
    const float*    lnw       = (const float*)d_in[7];
    const float*    lnb       = (const float*)d_in[8];
    float* out = (float*)d_out;

    const int N = in_sizes[0] / ND;   // 50000
    const int E = in_sizes[1] / ED;   // 800000

    // Workspace layout (~57.8 MB):
    char* ws = (char*)d_ws;
    float* wcc = (float*)ws;                              // 128*128 floats
    float* P   = (float*)(ws + 65536);                    // [N,128]
    float* m   = P + (size_t)N * ND;                      // [N,128]
    int*   ctr = (int*)(m + (size_t)N * ND);              // [E]
    int*   ngh = ctr + E;                                 // [E]

    hipMemsetAsync(m, 0, (size_t)N * ND * sizeof(float), stream);
    conv_idx_kernel<<<256, 256, 0, stream>>>(edge_idx, ctr, ngh, E);
    wcc_kernel<<<128, 128, 0, stream>>>(W_center, W_concat, wcc);
    // P = node_attr @ W_node
    gemm128_kernel<<<2048, 256, 0, stream>>>(node_attr, W_node, P, N);
    // C2 = node_attr @ wcc   (stored in d_out; consumed in-place by final)
    gemm128_kernel<<<2048, 256, 0, stream>>>(node_attr, wcc, out, N);
    // m[center] += P[neigh] * (edge_attr @ W_edge)
    edge_kernel<<<4096, 256, 0, stream>>>(edge_attr, ctr, ngh, W_edge, P, m, E);
    // out = LN(C2 + m @ W_bot)
    final_kernel<<<2048, 256, 0, stream>>>(out, m, W_concat + ND * ND, lnw, lnb,
                                           out, N);
}

// Round 2
// 873.493 us; speedup vs baseline: 1.9791x; 1.9791x over previous
//
#include <hip/hip_runtime.h>

#define ND 128   // node feature dim D
#define ED 32    // edge radial basis dim
#define LN_EPS 1e-5f

// ---------------------------------------------------------------------------
// Detect int64-vs-int32 edge_index, convert to int32 ctr/ngh, and histogram
// the center indices into cnt[] (cnt must be zeroed before launch).
// ---------------------------------------------------------------------------
__global__ void conv_hist_kernel(const unsigned* __restrict__ raw,
                                 int* __restrict__ ctr, int* __restrict__ ngh,
                                 int* __restrict__ cnt, int E) {
    __shared__ int s_is64;
    if (threadIdx.x == 0) {
        unsigned acc = 0;
        for (int i = 1; i < 512; i += 2) acc |= raw[i];
        s_is64 = (acc == 0) ? 1 : 0;
    }
    __syncthreads();
    const int is64 = s_is64;
    const int tid = blockIdx.x * blockDim.x + threadIdx.x;
    const int stride = gridDim.x * blockDim.x;
    if (is64) {
        for (int e = tid; e < E; e += stride) {
            const int c = (int)raw[(size_t)2 * e];
            ctr[e] = c;
            ngh[e] = (int)raw[(size_t)2 * E + (size_t)2 * e];
            atomicAdd(&cnt[c], 1);
        }
    } else {
        for (int e = tid; e < E; e += stride) {
            const int c = (int)raw[e];
            ctr[e] = c;
            ngh[e] = (int)raw[(size_t)E + e];
            atomicAdd(&cnt[c], 1);
        }
    }
}

// ---------------------------------------------------------------------------
// Single-block exclusive scan over cnt[0..N) -> base[0..N] (base[N]=E total).
// Also zeroes cur[0..N). 1024 threads, each owns a contiguous chunk.
// ---------------------------------------------------------------------------
__global__ __launch_bounds__(1024) void scan_kernel(
    const int* __restrict__ cnt, int* __restrict__ base,
    int* __restrict__ cur, int N) {
    __shared__ int part[1024];
    const int tid = threadIdx.x;
    const int chunk = (N + 1023) >> 10;
    const int lo = tid * chunk;
    const int hi = min(lo + chunk, N);
    int s = 0;
    for (int i = lo; i < hi; ++i) { s += cnt[i]; cur[i] = 0; }
    part[tid] = s;
    __syncthreads();
    // Hillis-Steele inclusive scan
    for (int off = 1; off < 1024; off <<= 1) {
        int v = 0;
        if (tid >= off) v = part[tid - off];
        __syncthreads();
        part[tid] += v;
        __syncthreads();
    }
    int excl = (tid > 0) ? part[tid - 1] : 0;
    for (int i = lo; i < hi; ++i) { base[i] = excl; excl += cnt[i]; }
    if (tid == 1023) base[N] = part[1023];
}

// ---------------------------------------------------------------------------
// Scatter edges into center-sorted order: eperm[pos]=e, nghperm[pos]=ngh[e].
// ---------------------------------------------------------------------------
__global__ void scatter_kernel(const int* __restrict__ ctr,
                               const int* __restrict__ ngh,
                               const int* __restrict__ base,
                               int* __restrict__ cur,
                               int* __restrict__ eperm,
                               int* __restrict__ nghperm, int E) {
    const int tid = blockIdx.x * blockDim.x + threadIdx.x;
    const int stride = gridDim.x * blockDim.x;
    for (int e = tid; e < E; e += stride) {
        const int c = ctr[e];
        const int pos = base[c] + atomicAdd(&cur[c], 1);
        eperm[pos] = e;
        nghperm[pos] = ngh[e];
    }
}

// ---------------------------------------------------------------------------
// wcc = W_center_node @ W_concat[0:128, :]   (128x128, tiny)
// ---------------------------------------------------------------------------
__global__ void wcc_kernel(const float* __restrict__ Wc,
                           const float* __restrict__ Wcat,
                           float* __restrict__ wcc) {
    const int i = blockIdx.x;
    const int j = threadIdx.x;
    float acc = 0.f;
    for (int k = 0; k < ND; ++k)
        acc += Wc[i * ND + k] * Wcat[k * ND + j];
    wcc[i * ND + j] = acc;
}

// ---------------------------------------------------------------------------
// out[M,128] = A[M,128] @ W[128,128], fp32. W in LDS; 8 rows per block-iter;
// each thread owns 4 consecutive cols; row broadcast via __shfl.
// ---------------------------------------------------------------------------
__global__ __launch_bounds__(256) void gemm128_kernel(
    const float* __restrict__ A, const float* __restrict__ W,
    float* __restrict__ out, int M) {
    __shared__ float Ws[ND * ND];
    for (int i = threadIdx.x; i < ND * ND; i += 256) Ws[i] = W[i];
    __syncthreads();
    const int slot = threadIdx.x >> 5;
    const int j0 = (threadIdx.x & 31) * 4;
    for (int r0 = blockIdx.x * 8; r0 < M; r0 += gridDim.x * 8) {
        const int r = r0 + slot;
        float rv[4] = {0.f, 0.f, 0.f, 0.f};
        if (r < M) {
            const float4 t = *(const float4*)&A[(size_t)r * ND + j0];
            rv[0] = t.x; rv[1] = t.y; rv[2] = t.z; rv[3] = t.w;
        }
        float4 acc = {0.f, 0.f, 0.f, 0.f};
#pragma unroll
        for (int k = 0; k < ND; ++k) {
            const float a = __shfl(rv[k & 3], k >> 2, 32);
            const float4 w = *(const float4*)&Ws[k * ND + j0];
            acc.x += a * w.x; acc.y += a * w.y;
            acc.z += a * w.z; acc.w += a * w.w;
        }
        if (r < M) *(float4*)&out[(size_t)r * ND + j0] = acc;
    }
}

// ---------------------------------------------------------------------------
// Segmented edge reduction, no atomics.
// One 32-lane half-wave per node v; lane owns 4 consecutive cols (j0).
// For each edge p in [base[v], base[v+1]):
//   R = edge_attr[eperm[p]] @ W_edge  (W_edge staged in LDS)
//   acc += R * P[nghperm[p]]
// m[v] = acc (single coalesced write; every row written -> no memset needed).
// ---------------------------------------------------------------------------
__global__ __launch_bounds__(256) void seg_kernel(
    const int* __restrict__ base, const int* __restrict__ eperm,
    const int* __restrict__ nghperm, const float* __restrict__ edge_attr,
    const float* __restrict__ W_edge, const float* __restrict__ P,
    float* __restrict__ m, int N) {
    __shared__ float We[ED * ND];   // 16 KB
    for (int i = threadIdx.x; i < ED * ND; i += 256) We[i] = W_edge[i];
    __syncthreads();
    const int v = blockIdx.x * 8 + (threadIdx.x >> 5);
    const int j0 = (threadIdx.x & 31) * 4;
    int s = 0, t = 0;
    if (v < N) { s = base[v]; t = base[v + 1]; }
    float4 acc = {0.f, 0.f, 0.f, 0.f};
    for (int p = s; p < t; ++p) {
        const int e  = eperm[p];     // same addr across the 32-lane half
        const int nn = nghperm[p];
        const float4* ea4 = (const float4*)(edge_attr + (size_t)e * ED);
        float4 av[8];
#pragma unroll
        for (int i = 0; i < 8; ++i) av[i] = ea4[i];   // broadcast loads
        const float4 pr = *(const float4*)&P[(size_t)nn * ND + j0];
        float4 r = {0.f, 0.f, 0.f, 0.f};
#pragma unroll
        for (int k = 0; k < ED; ++k) {
            const float a = ((const float*)&av[k >> 2])[k & 3];  // static idx
            const float4 w = *(const float4*)&We[k * ND + j0];
            r.x += a * w.x; r.y += a * w.y;
            r.z += a * w.z; r.w += a * w.w;
        }
        acc.x += r.x * pr.x; acc.y += r.y * pr.y;
        acc.z += r.z * pr.z; acc.w += r.w * pr.w;
    }
    if (v < N) *(float4*)&m[(size_t)v * ND + j0] = acc;
}

// ---------------------------------------------------------------------------
// out[r] = LayerNorm(C2[r] + m[r] @ W_bot) * lnw + lnb  (in-place on d_out)
// ---------------------------------------------------------------------------
__global__ __launch_bounds__(256) void final_kernel(
    const float* __restrict__ C2, const float* __restrict__ m,
    const float* __restrict__ Wb, const float* __restrict__ lnw,
    const float* __restrict__ lnb, float* __restrict__ out, int N) {
    __shared__ float Ws[ND * ND];
    for (int i = threadIdx.x; i < ND * ND; i += 256) Ws[i] = Wb[i];
    __syncthreads();
    const int slot = threadIdx.x >> 5;
    const int j0 = (threadIdx.x & 31) * 4;
    for (int r0 = blockIdx.x * 8; r0 < N; r0 += gridDim.x * 8) {
        const int r = r0 + slot;
        float mv[4] = {0.f, 0.f, 0.f, 0.f};
        float4 acc = {0.f, 0.f, 0.f, 0.f};
        if (r < N) {
            const float4 t = *(const float4*)&m[(size_t)r * ND + j0];
            mv[0] = t.x; mv[1] = t.y; mv[2] = t.z; mv[3] = t.w;
            acc = *(const float4*)&C2[(size_t)r * ND + j0];
        }
#pragma unroll
        for (int k = 0; k < ND; ++k) {
            const float a = __shfl(mv[k & 3], k >> 2, 32);
            const float4 w = *(const float4*)&Ws[k * ND + j0];
            acc.x += a * w.x; acc.y += a * w.y;
            acc.z += a * w.z; acc.w += a * w.w;
        }
        float s = acc.x + acc.y + acc.z + acc.w;
        s += __shfl_xor(s, 16); s += __shfl_xor(s, 8);
        s += __shfl_xor(s, 4);  s += __shfl_xor(s, 2); s += __shfl_xor(s, 1);
        const float mean = s * (1.f / ND);
        const float4 d = {acc.x - mean, acc.y - mean, acc.z - mean, acc.w - mean};
        float q = d.x * d.x + d.y * d.y + d.z * d.z + d.w * d.w;
        q += __shfl_xor(q, 16); q += __shfl_xor(q, 8);
        q += __shfl_xor(q, 4);  q += __shfl_xor(q, 2); q += __shfl_xor(q, 1);
        const float rstd = rsqrtf(q * (1.f / ND) + LN_EPS);
        const float4 w4 = *(const float4*)&lnw[j0];
        const float4 b4 = *(const float4*)&lnb[j0];
        if (r < N) {
            float4 o;
            o.x = d.x * rstd * w4.x + b4.x;
            o.y = d.y * rstd * w4.y + b4.y;
            o.z = d.z * rstd * w4.z + b4.z;
            o.w = d.w * rstd * w4.w + b4.w;
            *(float4*)&out[(size_t)r * ND + j0] = o;
        }
    }
}

// ---------------------------------------------------------------------------
extern "C" void kernel_launch(void* const* d_in, const int* in_sizes, int n_in,
                              void* d_out, int out_size, void* d_ws, size_t ws_size,
                              hipStream_t stream) {
    const float*    node_attr = (const float*)d_in[0];
    const float*    edge_attr = (const float*)d_in[1];
    const unsigned* edge_idx  = (const unsigned*)d_in[2];
    const float*    W_node    = (const float*)d_in[3];
    const float*    W_center  = (const float*)d_in[4];
    const float*    W_concat  = (const float*)d_in[5];
    const float*    W_edge    = (const float*)d_in[6];
    const float*    lnw       = (const float*)d_in[7];
    const float*    lnb       = (const float*)d_in[8];
    float* out = (float*)d_out;

    const int N = in_sizes[0] / ND;   // 50000
    const int E = in_sizes[1] / ED;   // 800000

    // Workspace layout (~65 MB):
    char* ws = (char*)d_ws;
    float* wcc     = (float*)ws;                          // 16384 f
    float* P       = (float*)(ws + 65536);                // [N,128]
    float* m       = P + (size_t)N * ND;                  // [N,128]
    int*   ctr     = (int*)(m + (size_t)N * ND);          // [E]
    int*   ngh     = ctr + E;                             // [E]
    int*   eperm   = ngh + E;                             // [E]
    int*   nghperm = eperm + E;                           // [E]
    int*   cnt     = nghperm + E;                         // [N]
    int*   base    = cnt + N;                             // [N+1]
    int*   cur     = base + N + 1;                        // [N]

    hipMemsetAsync(cnt, 0, (size_t)N * sizeof(int), stream);
    conv_hist_kernel<<<512, 256, 0, stream>>>(edge_idx, ctr, ngh, cnt, E);
    scan_kernel<<<1, 1024, 0, stream>>>(cnt, base, cur, N);
    scatter_kernel<<<512, 256, 0, stream>>>(ctr, ngh, base, cur, eperm,
                                            nghperm, E);
    wcc_kernel<<<128, 128, 0, stream>>>(W_center, W_concat, wcc);
    // P = node_attr @ W_node
    gemm128_kernel<<<2048, 256, 0, stream>>>(node_attr, W_node, P, N);
    // C2 = node_attr @ wcc (stored in d_out; consumed in-place by final)
    gemm128_kernel<<<2048, 256, 0, stream>>>(node_attr, wcc, out, N);
    // m[v] = sum over v's edges of (ea @ W_edge) * P[ngh]
    seg_kernel<<<(N + 7) / 8, 256, 0, stream>>>(base, eperm, nghperm,
                                                edge_attr, W_edge, P, m, N);
    // out = LN(C2 + m @ W_bot)
    final_kernel<<<2048, 256, 0, stream>>>(out, m, W_concat + ND * ND, lnw,
                                           lnb, out, N);
}